// Round 15
// baseline (2591.298 us; speedup 1.0000x reference)
//
#include <hip/hip_runtime.h>
#include <stdint.h>

#define T_STEPS 256
#define EMBD 10
#define MB 16          // batch rows per group
#define GROUPS 64      // 1024 / MB
#define JSPLIT 4       // CUs per group (N-shard)
#define NKIT 9         // K = 288 = 9 * 32 (256 h + 10 x + 1 bias + pad)

typedef __attribute__((ext_vector_type(8))) short bf16x8;
typedef __attribute__((ext_vector_type(4))) float f32x4;
typedef __attribute__((ext_vector_type(4))) int   i32x4;
typedef unsigned long long u64;

__device__ __forceinline__ unsigned short f2bf(float f) {
    union { float f; unsigned int u; } v; v.f = f;
    unsigned int u = v.u;
    unsigned int r = (u + 0x7FFFu + ((u >> 16) & 1u)) >> 16;  // RNE
    return (unsigned short)r;
}
__device__ __forceinline__ float sig_fast(float x) {
    return __frcp_rn(1.0f + exp2f(-1.4426950408889634f * x));
}
__device__ __forceinline__ float tanh_fast(float x) {
    return 1.0f - 2.0f * __frcp_rn(exp2f(2.8853900817779268f * x) + 1.0f);
}

// AGPR park/unpark -- correctness HW-proven (R11/R12 passed). Storage the
// VGPR allocator cannot restream.
__device__ __forceinline__ i32x4 park_agpr(i32x4 v) {
    i32x4 r;
    asm volatile("v_accvgpr_write_b32 %0, %4\n\t"
                 "v_accvgpr_write_b32 %1, %5\n\t"
                 "v_accvgpr_write_b32 %2, %6\n\t"
                 "v_accvgpr_write_b32 %3, %7"
                 : "=a"(r.x), "=a"(r.y), "=a"(r.z), "=a"(r.w)
                 : "v"(v.x), "v"(v.y), "v"(v.z), "v"(v.w));
    return r;
}
__device__ __forceinline__ i32x4 unpark_agpr(i32x4 a) {
    i32x4 r;
    asm("v_accvgpr_read_b32 %0, %4\n\t"
        "v_accvgpr_read_b32 %1, %5\n\t"
        "v_accvgpr_read_b32 %2, %6\n\t"
        "v_accvgpr_read_b32 %3, %7\n\t"
        "s_nop 1"
        : "=v"(r.x), "=v"(r.y), "=v"(r.z), "=v"(r.w)
        : "a"(a.x), "a"(a.y), "a"(a.z), "a"(a.w));
    return r;
}
__device__ __forceinline__ f32x4 mfma_v(i32x4 a, i32x4 b, f32x4 c) {
    return __builtin_amdgcn_mfma_f32_16x16x32_bf16(
        __builtin_bit_cast(bf16x8, a), __builtin_bit_cast(bf16x8, b), c, 0, 0, 0);
}

// ---------------------------------------------------------------------------
// K1: swizzled bf16 weights Wfull[288][1024] in MFMA B-frag order.
// Layout: [kit 0..8][ntile 0..63][lane 0..63] x 16B.
// Lane's 8 bf16: Wfull[k = kit*32 + (lane>>4)*8 + j][n = ntile*16 + (lane&15)]
// k<256 -> Wh[k][:], 256..265 -> Wx[k-256][:], 266 -> bias, else 0.
// ---------------------------------------------------------------------------
__global__ __launch_bounds__(64) void build_wswz(
    const float* __restrict__ Wgx, const float* __restrict__ Wgh, const float* __restrict__ bg,
    const float* __restrict__ Wix, const float* __restrict__ Wih, const float* __restrict__ bi,
    const float* __restrict__ Wfx, const float* __restrict__ Wfh, const float* __restrict__ bf_,
    const float* __restrict__ Wox, const float* __restrict__ Woh, const float* __restrict__ bo,
    unsigned short* __restrict__ wswz)
{
    int g   = blockIdx.x / NKIT;   // ntile
    int kit = blockIdx.x % NKIT;
    int lane = threadIdx.x;
    int n = g * 16 + (lane & 15);
    int q = n >> 8;
    int col = n & 255;
    const float* Wh = (q == 0) ? Wgh : (q == 1) ? Wih : (q == 2) ? Wfh : Woh;
    const float* Wx = (q == 0) ? Wgx : (q == 1) ? Wix : (q == 2) ? Wfx : Wox;
    const float* bb = (q == 0) ? bg  : (q == 1) ? bi  : (q == 2) ? bf_ : bo;
    int k0 = kit * 32 + (lane >> 4) * 8;

    int4 out;
    unsigned short* p = (unsigned short*)&out;
#pragma unroll
    for (int jx = 0; jx < 8; jx++) {
        int k = k0 + jx;
        float v = 0.0f;
        if (k < 256)             v = Wh[k * 256 + col];
        else if (k < 256 + EMBD) v = Wx[(k - 256) * 256 + col];
        else if (k == 266)       v = bb[col];
        p[jx] = f2bf(v);
    }
    ((int4*)wswz)[(kit * 64 + g) * 64 + lane] = out;
}

// ---------------------------------------------------------------------------
// K2: N-sharded persistent LSTM. 256 blocks x 256 threads (4 waves, 1/SIMD,
// waves_per_eu(1,1) -> 256 arch + 256 AGPR budget, honored per R11).
// Block b: g = b&63 (batch rows 16g..), j = b>>6 (hcols 64j..64j+64).
// Wave w: cp = 4j+w, hcols [16cp, 16cp+16) x 4 gates -> 36 B-frags, ALL
// resident (kits 0-3 parked AGPR, kits 4-8 arch VGPR). ZERO per-step B
// streaming -> consumer polling cannot evict anything hot (R3's spiral).
// Exchange per step: 2 KB coalesced PLAIN stores + release fence + flag;
// RELAXED lane-0 polling + s_sleep + one acquire fence + plain loads.
// Parity-double-buffered blobs, monotonic flags (R3-proven protocol).
// Same-XCD peers (b mod 8 = g mod 8) is a perf heuristic only.
// ---------------------------------------------------------------------------
__global__ __launch_bounds__(256)
__attribute__((amdgpu_waves_per_eu(1, 1)))
void lstm_main(
    const int*   __restrict__ xtok,   // [1024][1][256]
    const float* __restrict__ emb,    // [32000][10]
    const float* __restrict__ Wph,    // [256][10]
    const float* __restrict__ bp,     // [10]
    const unsigned short* __restrict__ wswz,
    u64*  __restrict__ blobG,         // [2][256][256] u64
    int*  __restrict__ flags,         // [256][16] ints (64B per block)
    float* __restrict__ out)          // [1024][10]
{
    __shared__ __align__(16) unsigned short A_lds[2][8 * 64 * 8];   // 16 KB (h kits 0-7)
    __shared__ __align__(16) unsigned short A8_lds[2][64 * 8];      // 2 KB (kit 8)
    __shared__ float outacc[MB * 10];

    const int tid  = threadIdx.x;
    const int w    = tid >> 6;        // wave 0..3
    const int lane = tid & 63;
    const int quad = lane >> 4;
    const int l15  = lane & 15;
    const int b    = blockIdx.x;
    const int g    = b & 63;
    const int j    = b >> 6;
    const int cp   = 4 * j + w;       // col-position 0..15

    const i32x4* Bg = (const i32x4*)wswz;

    // --- B fully resident: kits 0-3 parked in AGPR, kits 4-8 in arch VGPR ---
    i32x4 bag[4][4];   // [kit][gate]
#pragma unroll
    for (int s = 0; s < 4; s++)
#pragma unroll
        for (int gt = 0; gt < 4; gt++)
            bag[s][gt] = park_agpr(Bg[(s * 64 + gt * 16 + cp) * 64 + lane]);
    i32x4 brg[5][4];   // kits 4..8
#pragma unroll
    for (int s = 0; s < 5; s++)
#pragma unroll
        for (int gt = 0; gt < 4; gt++)
            brg[s][gt] = Bg[((4 + s) * 64 + gt * 16 + cp) * 64 + lane];

    // --- init A double buffer: zeros, bias row (both), x_0 (buf 0) ---
    {
        int4 z4 = {0, 0, 0, 0};
        for (int i = tid; i < 512; i += 256) ((int4*)A_lds)[i] = z4;
        if (tid < 128) ((int4*)A8_lds)[tid] = z4;
    }
    __syncthreads();
    if (tid < 16) {
        // kit8 local k=10 (bias=1.0): lp = m+16, elem 2
        A8_lds[0][(16 + tid) * 8 + 2] = 0x3F80;
        A8_lds[1][(16 + tid) * 8 + 2] = 0x3F80;
    }
    if (tid < 160) {
        int row = tid / 10, e = tid - row * 10;
        int tok = xtok[(g * MB + row) * T_STEPS + 0];
        float v = emb[tok * EMBD + e];
        A8_lds[0][(row + 16 * (e >> 3)) * 8 + (e & 7)] = f2bf(v);
    }
    __syncthreads();

    float c[4], hreg[4];
#pragma unroll
    for (int r = 0; r < 4; r++) { c[r] = 0.0f; hreg[r] = 0.0f; }

    const int hcol   = cp * 16 + l15;
    const int lpbase = 16 * ((hcol >> 3) & 3);
    const int kofs   = (hcol >> 5) * 64;
    int* myflag = flags + b * 16;

    for (int t = 0; t < T_STEPS; t++) {
        const i32x4* Ab  = (const i32x4*)A_lds[t & 1];
        const i32x4* A8b = (const i32x4*)A8_lds[t & 1];
        unsigned short* Aw  = A_lds[(t + 1) & 1];
        unsigned short* A8w = A8_lds[(t + 1) & 1];

        // A-frags (full K) from LDS
        i32x4 aA[9];
#pragma unroll
        for (int k = 0; k < 8; k++) aA[k] = Ab[k * 64 + lane];
        aA[8] = A8b[lane];

        f32x4 acc[4];
#pragma unroll
        for (int gt = 0; gt < 4; gt++) acc[gt] = (f32x4){0.f, 0.f, 0.f, 0.f};

        // arch kits 4..8 (builtin; compiler handles VALU->MFMA srcC hazard)
#pragma unroll
        for (int s = 0; s < 5; s++)
#pragma unroll
            for (int gt = 0; gt < 4; gt++)
                acc[gt] = mfma_v(aA[4 + s], brg[s][gt], acc[gt]);
        // parked kits 0..3
#pragma unroll
        for (int s = 0; s < 4; s++)
#pragma unroll
            for (int gt = 0; gt < 4; gt++)
                acc[gt] = mfma_v(aA[s], unpark_agpr(bag[s][gt]), acc[gt]);

        // gates: lane owns rows m=quad*4+r, col hcol (all 4 gates same reg)
#pragma unroll
        for (int r = 0; r < 4; r++) {
            float gg = tanh_fast(acc[0][r]);
            float ii = sig_fast(acc[1][r]);
            float ff = sig_fast(acc[2][r]);
            float oo = sig_fast(acc[3][r]);
            float cn = gg * ii + c[r] * ff;
            c[r] = cn;
            float hh = tanh_fast(cn) * oo;
            hreg[r] = hh;
            int m = quad * 4 + r;
            Aw[(kofs + m + lpbase) * 8 + (hcol & 7)] = f2bf(hh);
        }
        if (t == T_STEPS - 1) break;
        __syncthreads();  // B1: all own h(t+1) in Aw

        // --- export own 2KB (kits 2j..2j+1) as coalesced PLAIN stores ---
        {
            u64 v = ((const u64*)Aw)[256 * j + tid];
            blobG[((size_t)((t + 1) & 1) * 256 + b) * 256 + tid] = v;
        }
        asm volatile("s_waitcnt vmcnt(0)" ::: "memory");
        __syncthreads();  // B2: all exports drained
        if (tid == 0) {
            __builtin_amdgcn_fence(__ATOMIC_RELEASE, "agent");
            __hip_atomic_store(myflag, t + 1, __ATOMIC_RELAXED,
                               __HIP_MEMORY_SCOPE_AGENT);
        }

        // --- import 3 peers (waves 1..3); wave 0 gathers x(t+1) ---
        if (w != 0) {
            int jj = (j + w) & 3;
            int pb = jj * 64 + g;
            int* pf = flags + pb * 16;
            int fl = 0;
            while (true) {
                if (lane == 0)
                    fl = __hip_atomic_load(pf, __ATOMIC_RELAXED,
                                           __HIP_MEMORY_SCOPE_AGENT);
                fl = __shfl(fl, 0, 64);
                if (fl >= t + 1) break;
                __builtin_amdgcn_s_sleep(1);
            }
            __builtin_amdgcn_fence(__ATOMIC_ACQUIRE, "agent");
            const u64* src = blobG + ((size_t)((t + 1) & 1) * 256 + pb) * 256;
            u64* Aw64 = (u64*)Aw;
#pragma unroll
            for (int s = 0; s < 4; s++)
                Aw64[jj * 256 + lane + 64 * s] = src[lane + 64 * s];
        } else {
#pragma unroll
            for (int it = 0; it < 3; it++) {
                int idx = lane + 64 * it;
                if (idx < 160) {
                    int row = (idx * 205) >> 11;      // idx/10 for idx<160
                    int e = idx - row * 10;
                    int tok = xtok[(g * MB + row) * T_STEPS + (t + 1)];
                    float v = emb[tok * EMBD + e];
                    A8w[(row + 16 * (e >> 3)) * 8 + (e & 7)] = f2bf(v);
                }
            }
        }
        __syncthreads();  // B3: A(t+1) fully built
    }

    // --- epilogue: partial out over this wave's 16 hcols ---
    float part[4][10];
#pragma unroll
    for (int r = 0; r < 4; r++)
#pragma unroll
        for (int cl = 0; cl < 10; cl++)
            part[r][cl] = hreg[r] * Wph[hcol * 10 + cl];
#pragma unroll
    for (int off = 1; off < 16; off <<= 1)
#pragma unroll
        for (int r = 0; r < 4; r++)
#pragma unroll
            for (int cl = 0; cl < 10; cl++)
                part[r][cl] += __shfl_xor(part[r][cl], off, 64);

    if (tid < MB * 10) outacc[tid] = 0.0f;
    __syncthreads();
    if (l15 == 0) {
#pragma unroll
        for (int r = 0; r < 4; r++) {
            int m = quad * 4 + r;
#pragma unroll
            for (int cl = 0; cl < 10; cl++)
                atomicAdd(&outacc[m * 10 + cl], part[r][cl]);
        }
    }
    __syncthreads();
    if (tid < MB * 10) {
        int m = tid / 10, cl = tid - m * 10;
        float v = outacc[tid] + (j == 0 ? bp[cl] : 0.0f);
        atomicAdd(&out[(g * MB + m) * 10 + cl], v);
    }
}

extern "C" void kernel_launch(void* const* d_in, const int* in_sizes, int n_in,
                              void* d_out, int out_size, void* d_ws, size_t ws_size,
                              hipStream_t stream) {
    const int*   x    = (const int*)  d_in[0];
    const float* emb  = (const float*)d_in[1];
    const float* Wgx  = (const float*)d_in[2];
    const float* Wgh  = (const float*)d_in[3];
    const float* bg   = (const float*)d_in[4];
    const float* Wix  = (const float*)d_in[5];
    const float* Wih  = (const float*)d_in[6];
    const float* bi   = (const float*)d_in[7];
    const float* Wfx  = (const float*)d_in[8];
    const float* Wfh  = (const float*)d_in[9];
    const float* bf_  = (const float*)d_in[10];
    const float* Wox  = (const float*)d_in[11];
    const float* Woh  = (const float*)d_in[12];
    const float* bo   = (const float*)d_in[13];
    const float* Wph  = (const float*)d_in[14];
    const float* bp   = (const float*)d_in[15];

    char* ws = (char*)d_ws;
    unsigned short* wswz = (unsigned short*)ws;                    // 576 KB
    u64*  blobG = (u64*)(ws + 9 * 64 * 64 * 16);                   // 1 MB
    int*  flags = (int*)(ws + 9 * 64 * 64 * 16 + 2 * 256 * 2048);  // 16 KB

    hipMemsetAsync(flags, 0, 256 * 16 * sizeof(int), stream);
    hipMemsetAsync(d_out, 0, 1024 * 10 * sizeof(float), stream);

    build_wswz<<<GROUPS * NKIT, 64, 0, stream>>>(Wgx, Wgh, bg, Wix, Wih, bi,
                                                 Wfx, Wfh, bf_, Wox, Woh, bo, wswz);
    lstm_main<<<GROUPS * JSPLIT, 256, 0, stream>>>(x, emb, Wph, bp, wswz,
                                                   blobG, flags, (float*)d_out);
}

// Round 16
// 1667.093 us; speedup vs baseline: 1.5544x; 1.5544x over previous
//
#include <hip/hip_runtime.h>
#include <stdint.h>

#define T_STEPS 256
#define EMBD 10
#define MB 16          // batch rows per block
#define NBLK 64        // 1024 / MB
#define NKIT 9         // K = 288 = 9 * 32 (256 h + 10 x + 1 bias + pad)

typedef __attribute__((ext_vector_type(8))) short bf16x8;
typedef __attribute__((ext_vector_type(4))) float f32x4;
typedef __attribute__((ext_vector_type(4))) int   i32x4;

__device__ __forceinline__ unsigned short f2bf(float f) {
    union { float f; unsigned int u; } v; v.f = f;
    unsigned int u = v.u;
    unsigned int r = (u + 0x7FFFu + ((u >> 16) & 1u)) >> 16;  // RNE
    return (unsigned short)r;
}
__device__ __forceinline__ float sig_fast(float x) {
    return __frcp_rn(1.0f + exp2f(-1.4426950408889634f * x));
}
__device__ __forceinline__ float tanh_fast(float x) {
    return 1.0f - 2.0f * __frcp_rn(exp2f(2.8853900817779268f * x) + 1.0f);
}

// AGPR park/unpark -- HW-proven (R11/R12 passed). Storage the VGPR
// allocator cannot restream or spill.
__device__ __forceinline__ i32x4 park_agpr(i32x4 v) {
    i32x4 r;
    asm volatile("v_accvgpr_write_b32 %0, %4\n\t"
                 "v_accvgpr_write_b32 %1, %5\n\t"
                 "v_accvgpr_write_b32 %2, %6\n\t"
                 "v_accvgpr_write_b32 %3, %7"
                 : "=a"(r.x), "=a"(r.y), "=a"(r.z), "=a"(r.w)
                 : "v"(v.x), "v"(v.y), "v"(v.z), "v"(v.w));
    return r;
}
__device__ __forceinline__ i32x4 unpark_agpr(i32x4 a) {
    i32x4 r;
    asm("v_accvgpr_read_b32 %0, %4\n\t"
        "v_accvgpr_read_b32 %1, %5\n\t"
        "v_accvgpr_read_b32 %2, %6\n\t"
        "v_accvgpr_read_b32 %3, %7\n\t"
        "s_nop 1"
        : "=v"(r.x), "=v"(r.y), "=v"(r.z), "=v"(r.w)
        : "a"(a.x), "a"(a.y), "a"(a.z), "a"(a.w));
    return r;
}
__device__ __forceinline__ f32x4 mfma_v(i32x4 a, i32x4 b, f32x4 c) {
    return __builtin_amdgcn_mfma_f32_16x16x32_bf16(
        __builtin_bit_cast(bf16x8, a), __builtin_bit_cast(bf16x8, b), c, 0, 0, 0);
}

// ---------------------------------------------------------------------------
// K1: swizzled bf16 weights Wfull[288][1024] in MFMA B-frag order.
// Main region: [kit 0..8][ntile 0..63][lane] x 16B.
// Stream region (kits 4,7,8 only): [w 0..8][s 0..3][gate 0..4][u 0..2][lane]
// -- wave-major so each wave's 24 streamed frags are one contiguous 24 KB
// run with constant offsets (zero per-step address VALU, R12's spill driver).
// ---------------------------------------------------------------------------
__global__ __launch_bounds__(64) void build_wswz(
    const float* __restrict__ Wgx, const float* __restrict__ Wgh, const float* __restrict__ bg,
    const float* __restrict__ Wix, const float* __restrict__ Wih, const float* __restrict__ bi,
    const float* __restrict__ Wfx, const float* __restrict__ Wfh, const float* __restrict__ bf_,
    const float* __restrict__ Wox, const float* __restrict__ Woh, const float* __restrict__ bo,
    unsigned short* __restrict__ wswz, unsigned short* __restrict__ sbuf)
{
    int g   = blockIdx.x / NKIT;   // ntile
    int kit = blockIdx.x % NKIT;
    int lane = threadIdx.x;
    int n = g * 16 + (lane & 15);
    int q = n >> 8;
    int col = n & 255;
    const float* Wh = (q == 0) ? Wgh : (q == 1) ? Wih : (q == 2) ? Wfh : Woh;
    const float* Wx = (q == 0) ? Wgx : (q == 1) ? Wix : (q == 2) ? Wfx : Wox;
    const float* bb = (q == 0) ? bg  : (q == 1) ? bi  : (q == 2) ? bf_ : bo;
    int k0 = kit * 32 + (lane >> 4) * 8;

    int4 out;
    unsigned short* p = (unsigned short*)&out;
#pragma unroll
    for (int jx = 0; jx < 8; jx++) {
        int k = k0 + jx;
        float v = 0.0f;
        if (k < 256)             v = Wh[k * 256 + col];
        else if (k < 256 + EMBD) v = Wx[(k - 256) * 256 + col];
        else if (k == 266)       v = bb[col];
        p[jx] = f2bf(v);
    }
    ((int4*)wswz)[(kit * 64 + g) * 64 + lane] = out;

    if (kit == 4 || kit == 7 || kit == 8) {
        int s    = (kit == 4) ? 0 : (kit == 7) ? 1 : 2;
        int gate = g >> 4;
        int wv   = (g & 15) >> 1;
        int u    = g & 1;
        ((int4*)sbuf)[((((wv * 3 + s) * 4 + gate) * 2 + u) * 64) + lane] = out;
    }
}

// ---------------------------------------------------------------------------
// K2: persistent LSTM. 64 blocks x 512 threads (8 waves, 2 waves/SIMD;
// unified RF = 256/wave: 128 arch + 128 AGPR).
// Wave w owns hcols 32w+16u+l15 (u=0,1) x 4 gates: nt = gate*16 + 2w + u.
// B residency/wave: kits {0,1,2,3} parked in AGPR (32 frags = 128 AGPR),
// kits {5,6} in LDS (128 KB), kits {4,7,8-half} streamed (160 KB/step/CU)
// through a single 12-frag land buffer: consume -> reissue IN PLACE
// (t-invariant addresses). R12's second prefetch buffer (nland) pushed arch
// demand to ~170 at the 128 cap -> scratch spill (VGPR_Count=128,
// WRITE_SIZE +2 MB, 64% active VALU). This version's peak demand ~110.
// A-tile double-buffered in LDS; ONE barrier/step.
// ---------------------------------------------------------------------------
__global__ __launch_bounds__(512)
__attribute__((amdgpu_waves_per_eu(2, 2)))
void lstm_main(
    const int*   __restrict__ xtok,   // [1024][1][256]
    const float* __restrict__ emb,    // [32000][10]
    const float* __restrict__ Wph,    // [256][10]
    const float* __restrict__ bp,     // [10]
    const unsigned short* __restrict__ wswz,
    const unsigned short* __restrict__ sbuf,
    float* __restrict__ out)          // [1024][10]
{
    __shared__ __align__(16) unsigned short A_lds[2][8 * 64 * 8];   // 16 KB (kits 0-7)
    __shared__ __align__(16) unsigned short A8_lds[2][64 * 8];      // 2 KB (kit 8)
    __shared__ __align__(16) i32x4 B_lds[2 * 64 * 64];              // 128 KB (kits 5,6)
    __shared__ float outacc[MB * 10];

    const int tid  = threadIdx.x;
    const int w    = tid >> 6;        // wave 0..7
    const int lane = tid & 63;
    const int quad = lane >> 4;
    const int l15  = lane & 15;
    const int blk  = blockIdx.x;

    const int m_x = tid >> 4;         // x-gather: batch row 0..15 (tid<256)
    const int e_x = tid & 15;         // emb element (valid if <10)

    const i32x4* Bg  = (const i32x4*)wswz;
    const i32x4* SBw = (const i32x4*)sbuf + (size_t)w * (3 * 4 * 2 * 64);

    // --- prologue: LDS B-cache (kits 5,6) ---
    for (int i = tid; i < 2 * 64 * 64; i += 512)
        B_lds[i] = Bg[5 * 4096 + i];

    // --- AGPR-parked B: kits 0..3, [kit][gate][u] = 32 frags = 128 AGPR ---
    i32x4 bag[4][4][2];
#pragma unroll
    for (int s = 0; s < 4; s++)
#pragma unroll
        for (int g = 0; g < 4; g++)
#pragma unroll
            for (int u = 0; u < 2; u++)
                bag[s][g][u] = park_agpr(
                    Bg[(s * 64 + g * 16 + 2 * w + u) * 64 + lane]);

    // --- streamed land buffer: [s][gate] for current pass (u=0 first) ---
    // kit8 (s=2): lanes>=32 are zero and NEVER rewritten (predicated
    // reissue) -> zeros persist for the whole kernel.
    i32x4 land[12];
#pragma unroll
    for (int s = 0; s < 3; s++)
#pragma unroll
        for (int g = 0; g < 4; g++) {
            i32x4 v = (i32x4){0, 0, 0, 0};
            if (s < 2 || lane < 32)
                v = SBw[(((s * 4 + g) * 2 + 0) * 64) + lane];
            land[s * 4 + g] = v;
        }

    // --- init A double buffer: zeros, bias row (both), x_0 (buf 0) ---
    {
        int4 z4 = {0, 0, 0, 0};
        for (int i = tid; i < 1024; i += 512) ((int4*)A_lds)[i] = z4;
        if (tid < 128) ((int4*)A8_lds)[tid] = z4;
    }
    __syncthreads();
    if (tid < 16) {
        // kit8 local k=10 (bias=1.0): lp = m+16, elem 2
        A8_lds[0][(16 + tid) * 8 + 2] = 0x3F80;
        A8_lds[1][(16 + tid) * 8 + 2] = 0x3F80;
    }
    if (tid < 256 && e_x < EMBD) {
        int tok = xtok[(blk * MB + m_x) * T_STEPS + 0];
        float v = emb[tok * EMBD + e_x];
        A8_lds[0][(m_x + 16 * (e_x >> 3)) * 8 + (e_x & 7)] = f2bf(v);
    }
    __syncthreads();

    float c[2][4];
#pragma unroll
    for (int u = 0; u < 2; u++)
#pragma unroll
        for (int r = 0; r < 4; r++) c[u][r] = 0.0f;

    for (int t = 0; t < T_STEPS; t++) {
        const i32x4* Ab  = (const i32x4*)A_lds[t & 1];
        const i32x4* A8b = (const i32x4*)A8_lds[t & 1];
        unsigned short* Aw  = A_lds[(t + 1) & 1];
        unsigned short* A8w = A8_lds[(t + 1) & 1];

        // x(t+1) prefetch (independent; overlaps MFMA)
        float xval = 0.0f;
        const bool do_x = (t < T_STEPS - 1) && (tid < 256) && (e_x < EMBD);
        if ((t < T_STEPS - 1) && (tid < 256)) {
            int tok = xtok[(blk * MB + m_x) * T_STEPS + (t + 1)];
            if (e_x < EMBD) xval = emb[tok * EMBD + e_x];
        }

#pragma unroll
        for (int u = 0; u < 2; u++) {
            const int nu = 1 - u;  // reissue target (t-invariant addresses)

            f32x4 acc[4];
#pragma unroll
            for (int g = 0; g < 4; g++) acc[g] = (f32x4){0.f, 0.f, 0.f, 0.f};

            // --- streamed kits FIRST (loads landed last pass), then
            //     reissue each kit IN PLACE (no second buffer) ---
            {
                i32x4 a4 = Ab[4 * 64 + lane];
#pragma unroll
                for (int g = 0; g < 4; g++) acc[g] = mfma_v(a4, land[g], acc[g]);
#pragma unroll
                for (int g = 0; g < 4; g++)
                    land[g] = SBw[(((0 * 4 + g) * 2 + nu) * 64) + lane];
            }
            {
                i32x4 a7 = Ab[7 * 64 + lane];
#pragma unroll
                for (int g = 0; g < 4; g++) acc[g] = mfma_v(a7, land[4 + g], acc[g]);
#pragma unroll
                for (int g = 0; g < 4; g++)
                    land[4 + g] = SBw[(((1 * 4 + g) * 2 + nu) * 64) + lane];
            }
            {
                i32x4 a8 = A8b[lane];
#pragma unroll
                for (int g = 0; g < 4; g++) acc[g] = mfma_v(a8, land[8 + g], acc[g]);
                if (lane < 32) {
#pragma unroll
                    for (int g = 0; g < 4; g++)
                        land[8 + g] = SBw[(((2 * 4 + g) * 2 + nu) * 64) + lane];
                }
            }

            // --- AGPR kits 0..3 (unpark per use) ---
#pragma unroll
            for (int s = 0; s < 4; s++) {
                i32x4 as_ = Ab[s * 64 + lane];
#pragma unroll
                for (int g = 0; g < 4; g++)
                    acc[g] = mfma_v(as_, unpark_agpr(bag[s][g][u]), acc[g]);
            }
            // --- LDS kits 5,6 ---
            {
                i32x4 a5 = Ab[5 * 64 + lane];
#pragma unroll
                for (int g = 0; g < 4; g++)
                    acc[g] = mfma_v(a5, B_lds[(g * 16 + 2 * w + u) * 64 + lane], acc[g]);
            }
            {
                i32x4 a6 = Ab[6 * 64 + lane];
#pragma unroll
                for (int g = 0; g < 4; g++)
                    acc[g] = mfma_v(a6, B_lds[4096 + (g * 16 + 2 * w + u) * 64 + lane], acc[g]);
            }

            // gate math: z[m][n], m = quad*4+r, n = gate*256 + 32w + 16u + l15
            const int hcol = 32 * w + 16 * u + l15;
            const int lpbase = 16 * ((hcol >> 3) & 3);
#pragma unroll
            for (int r = 0; r < 4; r++) {
                float gg = tanh_fast(acc[0][r]);
                float ii = sig_fast(acc[1][r]);
                float ff = sig_fast(acc[2][r]);
                float oo = sig_fast(acc[3][r]);
                float cn = gg * ii + c[u][r] * ff;
                c[u][r] = cn;
                float hh = tanh_fast(cn) * oo;
                int m = quad * 4 + r;
                Aw[(w * 64 + m + lpbase) * 8 + (hcol & 7)] = f2bf(hh);
            }
        }
        if (t == T_STEPS - 1) break;
        if (do_x)
            A8w[(m_x + 16 * (e_x >> 3)) * 8 + (e_x & 7)] = f2bf(xval);
        __syncthreads();  // single barrier: A(t+1) complete
    }
    __syncthreads();

    // --- epilogue: re-read own h (bf16) from final A buffer, project ---
    const unsigned short* Af = A_lds[T_STEPS & 1];
    float part[4][10];
#pragma unroll
    for (int r = 0; r < 4; r++)
#pragma unroll
        for (int cl = 0; cl < 10; cl++) part[r][cl] = 0.0f;
#pragma unroll
    for (int u = 0; u < 2; u++) {
        const int hcol = 32 * w + 16 * u + l15;
        const int lpbase = 16 * ((hcol >> 3) & 3);
#pragma unroll
        for (int r = 0; r < 4; r++) {
            int m = quad * 4 + r;
            unsigned int hu = Af[(w * 64 + m + lpbase) * 8 + (hcol & 7)];
            union { unsigned int uu; float f; } cv; cv.uu = hu << 16;
            float hh = cv.f;
#pragma unroll
            for (int cl = 0; cl < 10; cl++)
                part[r][cl] += hh * Wph[hcol * 10 + cl];
        }
    }
#pragma unroll
    for (int off = 1; off < 16; off <<= 1)
#pragma unroll
        for (int r = 0; r < 4; r++)
#pragma unroll
            for (int cl = 0; cl < 10; cl++)
                part[r][cl] += __shfl_xor(part[r][cl], off, 64);

    if (tid < MB * 10) outacc[tid] = 0.0f;
    __syncthreads();
    if (l15 == 0) {
#pragma unroll
        for (int r = 0; r < 4; r++) {
            int m = quad * 4 + r;
#pragma unroll
            for (int cl = 0; cl < 10; cl++)
                atomicAdd(&outacc[m * 10 + cl], part[r][cl]);
        }
    }
    __syncthreads();
    if (tid < MB * 10) {
        int m = tid / 10, cl = tid - m * 10;
        out[(blk * MB + m) * 10 + cl] = outacc[tid] + bp[cl];
    }
}

extern "C" void kernel_launch(void* const* d_in, const int* in_sizes, int n_in,
                              void* d_out, int out_size, void* d_ws, size_t ws_size,
                              hipStream_t stream) {
    const int*   x    = (const int*)  d_in[0];
    const float* emb  = (const float*)d_in[1];
    const float* Wgx  = (const float*)d_in[2];
    const float* Wgh  = (const float*)d_in[3];
    const float* bg   = (const float*)d_in[4];
    const float* Wix  = (const float*)d_in[5];
    const float* Wih  = (const float*)d_in[6];
    const float* bi   = (const float*)d_in[7];
    const float* Wfx  = (const float*)d_in[8];
    const float* Wfh  = (const float*)d_in[9];
    const float* bf_  = (const float*)d_in[10];
    const float* Wox  = (const float*)d_in[11];
    const float* Woh  = (const float*)d_in[12];
    const float* bo   = (const float*)d_in[13];
    const float* Wph  = (const float*)d_in[14];
    const float* bp   = (const float*)d_in[15];

    char* ws = (char*)d_ws;
    unsigned short* wswz = (unsigned short*)ws;                   // 576 KB
    unsigned short* sbuf = (unsigned short*)(ws + 9 * 64 * 64 * 16); // 192 KB

    build_wswz<<<NBLK * NKIT, 64, 0, stream>>>(Wgx, Wgh, bg, Wix, Wih, bi,
                                               Wfx, Wfh, bf_, Wox, Woh, bo,
                                               wswz, sbuf);
    lstm_main<<<NBLK, 512, 0, stream>>>(x, emb, Wph, bp, wswz, sbuf,
                                        (float*)d_out);
}

// Round 17
// 1477.094 us; speedup vs baseline: 1.7543x; 1.1286x over previous
//
#include <hip/hip_runtime.h>
#include <stdint.h>

#define T_STEPS 256
#define EMBD 10
#define MB 16          // batch rows per block
#define NBLK 64        // 1024 / MB
#define NKIT 9         // K = 288 = 9 * 32 (256 h + 10 x + 1 bias + pad)

typedef __attribute__((ext_vector_type(8))) short bf16x8;
typedef __attribute__((ext_vector_type(4))) float f32x4;
typedef __attribute__((ext_vector_type(4))) int   i32x4;

__device__ __forceinline__ unsigned short f2bf(float f) {
    union { float f; unsigned int u; } v; v.f = f;
    unsigned int u = v.u;
    unsigned int r = (u + 0x7FFFu + ((u >> 16) & 1u)) >> 16;  // RNE
    return (unsigned short)r;
}
__device__ __forceinline__ float sig_fast(float x) {
    return __frcp_rn(1.0f + exp2f(-1.4426950408889634f * x));
}
__device__ __forceinline__ float tanh_fast(float x) {
    return 1.0f - 2.0f * __frcp_rn(exp2f(2.8853900817779268f * x) + 1.0f);
}

// AGPR park/unpark -- HW-proven (R11/R12/R16 passed). Storage the VGPR
// allocator cannot restream or spill.
__device__ __forceinline__ i32x4 park_agpr(i32x4 v) {
    i32x4 r;
    asm volatile("v_accvgpr_write_b32 %0, %4\n\t"
                 "v_accvgpr_write_b32 %1, %5\n\t"
                 "v_accvgpr_write_b32 %2, %6\n\t"
                 "v_accvgpr_write_b32 %3, %7"
                 : "=a"(r.x), "=a"(r.y), "=a"(r.z), "=a"(r.w)
                 : "v"(v.x), "v"(v.y), "v"(v.z), "v"(v.w));
    return r;
}
__device__ __forceinline__ i32x4 unpark_agpr(i32x4 a) {
    i32x4 r;
    asm("v_accvgpr_read_b32 %0, %4\n\t"
        "v_accvgpr_read_b32 %1, %5\n\t"
        "v_accvgpr_read_b32 %2, %6\n\t"
        "v_accvgpr_read_b32 %3, %7\n\t"
        "s_nop 1"
        : "=v"(r.x), "=v"(r.y), "=v"(r.z), "=v"(r.w)
        : "a"(a.x), "a"(a.y), "a"(a.z), "a"(a.w));
    return r;
}
__device__ __forceinline__ f32x4 mfma_v(i32x4 a, i32x4 b, f32x4 c) {
    return __builtin_amdgcn_mfma_f32_16x16x32_bf16(
        __builtin_bit_cast(bf16x8, a), __builtin_bit_cast(bf16x8, b), c, 0, 0, 0);
}

// ---------------------------------------------------------------------------
// K1: swizzled bf16 weights Wfull[288][1024] in MFMA B-frag order.
// Main region: [kit 0..8][ntile 0..63][lane] x 16B.
// Stream region (kits 4,7,8): [w][s][gate][u][lane] -- wave-major constant
// offsets (K2 uses s=0 (kit4), s=1 (kit7); s=2 written but unused now).
// ---------------------------------------------------------------------------
__global__ __launch_bounds__(64) void build_wswz(
    const float* __restrict__ Wgx, const float* __restrict__ Wgh, const float* __restrict__ bg,
    const float* __restrict__ Wix, const float* __restrict__ Wih, const float* __restrict__ bi,
    const float* __restrict__ Wfx, const float* __restrict__ Wfh, const float* __restrict__ bf_,
    const float* __restrict__ Wox, const float* __restrict__ Woh, const float* __restrict__ bo,
    unsigned short* __restrict__ wswz, unsigned short* __restrict__ sbuf)
{
    int g   = blockIdx.x / NKIT;   // ntile
    int kit = blockIdx.x % NKIT;
    int lane = threadIdx.x;
    int n = g * 16 + (lane & 15);
    int q = n >> 8;
    int col = n & 255;
    const float* Wh = (q == 0) ? Wgh : (q == 1) ? Wih : (q == 2) ? Wfh : Woh;
    const float* Wx = (q == 0) ? Wgx : (q == 1) ? Wix : (q == 2) ? Wfx : Wox;
    const float* bb = (q == 0) ? bg  : (q == 1) ? bi  : (q == 2) ? bf_ : bo;
    int k0 = kit * 32 + (lane >> 4) * 8;

    int4 out;
    unsigned short* p = (unsigned short*)&out;
#pragma unroll
    for (int jx = 0; jx < 8; jx++) {
        int k = k0 + jx;
        float v = 0.0f;
        if (k < 256)             v = Wh[k * 256 + col];
        else if (k < 256 + EMBD) v = Wx[(k - 256) * 256 + col];
        else if (k == 266)       v = bb[col];
        p[jx] = f2bf(v);
    }
    ((int4*)wswz)[(kit * 64 + g) * 64 + lane] = out;

    if (kit == 4 || kit == 7 || kit == 8) {
        int s    = (kit == 4) ? 0 : (kit == 7) ? 1 : 2;
        int gate = g >> 4;
        int wv   = (g & 15) >> 1;
        int u    = g & 1;
        ((int4*)sbuf)[((((wv * 3 + s) * 4 + gate) * 2 + u) * 64) + lane] = out;
    }
}

// ---------------------------------------------------------------------------
// K2: persistent LSTM. 64 blocks x 512 threads (8 waves, 2 waves/SIMD;
// unified RF = 256/wave: 128 arch + 128 AGPR).
// Wave w owns hcols 32w+16u+l15 (u=0,1) x 4 gates: nt = gate*16 + 2w + u.
// B residency/wave: kits {0,1,2,3} parked AGPR (128 AGPR), kits {5,6} LDS
// (128 KB), kit {8} ARCH-RESIDENT (8 frags = 32 regs), kits {4,7} streamed
// (128 KB/step/CU) via an 8-frag land buffer (32 regs), consume-then-
// reissue in place. Arch demand ~115 < 128: this is the first 2-wave/SIMD
// config with comfortable register headroom -- the spill-hypothesis test
// (every prior 2-wave config pinned VGPR_Count at exactly 128 with elevated
// WRITE_SIZE = scratch writebacks).
// ---------------------------------------------------------------------------
__global__ __launch_bounds__(512)
__attribute__((amdgpu_waves_per_eu(2, 2)))
void lstm_main(
    const int*   __restrict__ xtok,   // [1024][1][256]
    const float* __restrict__ emb,    // [32000][10]
    const float* __restrict__ Wph,    // [256][10]
    const float* __restrict__ bp,     // [10]
    const unsigned short* __restrict__ wswz,
    const unsigned short* __restrict__ sbuf,
    float* __restrict__ out)          // [1024][10]
{
    __shared__ __align__(16) unsigned short A_lds[2][8 * 64 * 8];   // 16 KB (kits 0-7)
    __shared__ __align__(16) unsigned short A8_lds[2][64 * 8];      // 2 KB (kit 8)
    __shared__ __align__(16) i32x4 B_lds[2 * 64 * 64];              // 128 KB (kits 5,6)
    __shared__ float outacc[MB * 10];

    const int tid  = threadIdx.x;
    const int w    = tid >> 6;        // wave 0..7
    const int lane = tid & 63;
    const int quad = lane >> 4;
    const int l15  = lane & 15;
    const int blk  = blockIdx.x;

    const int m_x = tid >> 4;         // x-gather: batch row 0..15 (tid<256)
    const int e_x = tid & 15;         // emb element (valid if <10)

    const i32x4* Bg  = (const i32x4*)wswz;
    const i32x4* SBw = (const i32x4*)sbuf + (size_t)w * (3 * 4 * 2 * 64);

    // --- prologue: LDS B-cache (kits 5,6) ---
    for (int i = tid; i < 2 * 64 * 64; i += 512)
        B_lds[i] = Bg[5 * 4096 + i];

    // --- AGPR-parked B: kits 0..3, [kit][gate][u] = 32 frags = 128 AGPR ---
    i32x4 bag[4][4][2];
#pragma unroll
    for (int s = 0; s < 4; s++)
#pragma unroll
        for (int g = 0; g < 4; g++)
#pragma unroll
            for (int u = 0; u < 2; u++)
                bag[s][g][u] = park_agpr(
                    Bg[(s * 64 + g * 16 + 2 * w + u) * 64 + lane]);

    // --- arch-resident kit 8: [gate][u] = 8 frags = 32 regs ---
    i32x4 b8[4][2];
#pragma unroll
    for (int g = 0; g < 4; g++)
#pragma unroll
        for (int u = 0; u < 2; u++)
            b8[g][u] = Bg[(8 * 64 + g * 16 + 2 * w + u) * 64 + lane];

    // --- streamed land buffer: kits 4 (0..3) and 7 (4..7), current u ---
    i32x4 land[8];
#pragma unroll
    for (int g = 0; g < 4; g++) {
        land[g]     = SBw[(((0 * 4 + g) * 2 + 0) * 64) + lane];
        land[4 + g] = SBw[(((1 * 4 + g) * 2 + 0) * 64) + lane];
    }

    // --- init A double buffer: zeros, bias row (both), x_0 (buf 0) ---
    {
        int4 z4 = {0, 0, 0, 0};
        for (int i = tid; i < 1024; i += 512) ((int4*)A_lds)[i] = z4;
        if (tid < 128) ((int4*)A8_lds)[tid] = z4;
    }
    __syncthreads();
    if (tid < 16) {
        // kit8 local k=10 (bias=1.0): lp = m+16, elem 2
        A8_lds[0][(16 + tid) * 8 + 2] = 0x3F80;
        A8_lds[1][(16 + tid) * 8 + 2] = 0x3F80;
    }
    if (tid < 256 && e_x < EMBD) {
        int tok = xtok[(blk * MB + m_x) * T_STEPS + 0];
        float v = emb[tok * EMBD + e_x];
        A8_lds[0][(m_x + 16 * (e_x >> 3)) * 8 + (e_x & 7)] = f2bf(v);
    }
    __syncthreads();

    float c[2][4];
#pragma unroll
    for (int u = 0; u < 2; u++)
#pragma unroll
        for (int r = 0; r < 4; r++) c[u][r] = 0.0f;

    for (int t = 0; t < T_STEPS; t++) {
        const i32x4* Ab  = (const i32x4*)A_lds[t & 1];
        const i32x4* A8b = (const i32x4*)A8_lds[t & 1];
        unsigned short* Aw  = A_lds[(t + 1) & 1];
        unsigned short* A8w = A8_lds[(t + 1) & 1];

        // x(t+1) prefetch (independent; overlaps MFMA)
        float xval = 0.0f;
        const bool do_x = (t < T_STEPS - 1) && (tid < 256) && (e_x < EMBD);
        if ((t < T_STEPS - 1) && (tid < 256)) {
            int tok = xtok[(blk * MB + m_x) * T_STEPS + (t + 1)];
            if (e_x < EMBD) xval = emb[tok * EMBD + e_x];
        }

#pragma unroll
        for (int u = 0; u < 2; u++) {
            const int nu = 1 - u;  // reissue target (t-invariant addresses)

            f32x4 acc[4];
#pragma unroll
            for (int g = 0; g < 4; g++) acc[g] = (f32x4){0.f, 0.f, 0.f, 0.f};

            // --- streamed kits 4,7 FIRST (loads landed last pass) ---
            {
                i32x4 a4 = Ab[4 * 64 + lane];
#pragma unroll
                for (int g = 0; g < 4; g++) acc[g] = mfma_v(a4, land[g], acc[g]);
            }
            {
                i32x4 a7 = Ab[7 * 64 + lane];
#pragma unroll
                for (int g = 0; g < 4; g++) acc[g] = mfma_v(a7, land[4 + g], acc[g]);
            }
            // reissue both kits in place for next pass
#pragma unroll
            for (int g = 0; g < 4; g++)
                land[g] = SBw[(((0 * 4 + g) * 2 + nu) * 64) + lane];
#pragma unroll
            for (int g = 0; g < 4; g++)
                land[4 + g] = SBw[(((1 * 4 + g) * 2 + nu) * 64) + lane];

            // --- kit 8 (arch-resident) ---
            {
                i32x4 a8 = A8b[lane];
#pragma unroll
                for (int g = 0; g < 4; g++)
                    acc[g] = mfma_v(a8, b8[g][u], acc[g]);
            }
            // --- AGPR kits 0..3 (unpark per use) ---
#pragma unroll
            for (int s = 0; s < 4; s++) {
                i32x4 as_ = Ab[s * 64 + lane];
#pragma unroll
                for (int g = 0; g < 4; g++)
                    acc[g] = mfma_v(as_, unpark_agpr(bag[s][g][u]), acc[g]);
            }
            // --- LDS kits 5,6 ---
            {
                i32x4 a5 = Ab[5 * 64 + lane];
#pragma unroll
                for (int g = 0; g < 4; g++)
                    acc[g] = mfma_v(a5, B_lds[(g * 16 + 2 * w + u) * 64 + lane], acc[g]);
            }
            {
                i32x4 a6 = Ab[6 * 64 + lane];
#pragma unroll
                for (int g = 0; g < 4; g++)
                    acc[g] = mfma_v(a6, B_lds[4096 + (g * 16 + 2 * w + u) * 64 + lane], acc[g]);
            }

            // gate math: z[m][n], m = quad*4+r, n = gate*256 + 32w + 16u + l15
            const int hcol = 32 * w + 16 * u + l15;
            const int lpbase = 16 * ((hcol >> 3) & 3);
#pragma unroll
            for (int r = 0; r < 4; r++) {
                float gg = tanh_fast(acc[0][r]);
                float ii = sig_fast(acc[1][r]);
                float ff = sig_fast(acc[2][r]);
                float oo = sig_fast(acc[3][r]);
                float cn = gg * ii + c[u][r] * ff;
                c[u][r] = cn;
                float hh = tanh_fast(cn) * oo;
                int m = quad * 4 + r;
                Aw[(w * 64 + m + lpbase) * 8 + (hcol & 7)] = f2bf(hh);
            }
        }
        if (t == T_STEPS - 1) break;
        if (do_x)
            A8w[(m_x + 16 * (e_x >> 3)) * 8 + (e_x & 7)] = f2bf(xval);
        __syncthreads();  // single barrier: A(t+1) complete
    }
    __syncthreads();

    // --- epilogue: re-read own h (bf16) from final A buffer, project ---
    const unsigned short* Af = A_lds[T_STEPS & 1];
    float part[4][10];
#pragma unroll
    for (int r = 0; r < 4; r++)
#pragma unroll
        for (int cl = 0; cl < 10; cl++) part[r][cl] = 0.0f;
#pragma unroll
    for (int u = 0; u < 2; u++) {
        const int hcol = 32 * w + 16 * u + l15;
        const int lpbase = 16 * ((hcol >> 3) & 3);
#pragma unroll
        for (int r = 0; r < 4; r++) {
            int m = quad * 4 + r;
            unsigned int hu = Af[(w * 64 + m + lpbase) * 8 + (hcol & 7)];
            union { unsigned int uu; float f; } cv; cv.uu = hu << 16;
            float hh = cv.f;
#pragma unroll
            for (int cl = 0; cl < 10; cl++)
                part[r][cl] += hh * Wph[hcol * 10 + cl];
        }
    }
#pragma unroll
    for (int off = 1; off < 16; off <<= 1)
#pragma unroll
        for (int r = 0; r < 4; r++)
#pragma unroll
            for (int cl = 0; cl < 10; cl++)
                part[r][cl] += __shfl_xor(part[r][cl], off, 64);

    if (tid < MB * 10) outacc[tid] = 0.0f;
    __syncthreads();
    if (l15 == 0) {
#pragma unroll
        for (int r = 0; r < 4; r++) {
            int m = quad * 4 + r;
#pragma unroll
            for (int cl = 0; cl < 10; cl++)
                atomicAdd(&outacc[m * 10 + cl], part[r][cl]);
        }
    }
    __syncthreads();
    if (tid < MB * 10) {
        int m = tid / 10, cl = tid - m * 10;
        out[(blk * MB + m) * 10 + cl] = outacc[tid] + bp[cl];
    }
}

extern "C" void kernel_launch(void* const* d_in, const int* in_sizes, int n_in,
                              void* d_out, int out_size, void* d_ws, size_t ws_size,
                              hipStream_t stream) {
    const int*   x    = (const int*)  d_in[0];
    const float* emb  = (const float*)d_in[1];
    const float* Wgx  = (const float*)d_in[2];
    const float* Wgh  = (const float*)d_in[3];
    const float* bg   = (const float*)d_in[4];
    const float* Wix  = (const float*)d_in[5];
    const float* Wih  = (const float*)d_in[6];
    const float* bi   = (const float*)d_in[7];
    const float* Wfx  = (const float*)d_in[8];
    const float* Wfh  = (const float*)d_in[9];
    const float* bf_  = (const float*)d_in[10];
    const float* Wox  = (const float*)d_in[11];
    const float* Woh  = (const float*)d_in[12];
    const float* bo   = (const float*)d_in[13];
    const float* Wph  = (const float*)d_in[14];
    const float* bp   = (const float*)d_in[15];

    char* ws = (char*)d_ws;
    unsigned short* wswz = (unsigned short*)ws;                   // 576 KB
    unsigned short* sbuf = (unsigned short*)(ws + 9 * 64 * 64 * 16); // 192 KB

    build_wswz<<<NBLK * NKIT, 64, 0, stream>>>(Wgx, Wgh, bg, Wix, Wih, bi,
                                               Wfx, Wfh, bf_, Wox, Woh, bo,
                                               wswz, sbuf);
    lstm_main<<<NBLK, 512, 0, stream>>>(x, emb, Wph, bp, wswz, sbuf,
                                        (float*)d_out);
}

// Round 18
// 1439.336 us; speedup vs baseline: 1.8003x; 1.0262x over previous
//
#include <hip/hip_runtime.h>
#include <stdint.h>

#define T_STEPS 256
#define EMBD 10
#define MB 16          // batch rows per block
#define NBLK 64        // 1024 / MB
#define NKIT 9         // K = 288 = 9 * 32 (256 h + 10 x + 1 bias + pad)

typedef __attribute__((ext_vector_type(8))) short bf16x8;
typedef __attribute__((ext_vector_type(4))) float f32x4;
typedef __attribute__((ext_vector_type(4))) int   i32x4;

__device__ __forceinline__ unsigned short f2bf(float f) {
    union { float f; unsigned int u; } v; v.f = f;
    unsigned int u = v.u;
    unsigned int r = (u + 0x7FFFu + ((u >> 16) & 1u)) >> 16;  // RNE
    return (unsigned short)r;
}
__device__ __forceinline__ float sig_fast(float x) {
    return __frcp_rn(1.0f + exp2f(-1.4426950408889634f * x));
}
__device__ __forceinline__ float tanh_fast(float x) {
    return 1.0f - 2.0f * __frcp_rn(exp2f(2.8853900817779268f * x) + 1.0f);
}

// AGPR park/unpark -- HW-proven (R11/R12/R16/R17 passed). Storage the VGPR
// allocator cannot restream or spill.
__device__ __forceinline__ i32x4 park_agpr(i32x4 v) {
    i32x4 r;
    asm volatile("v_accvgpr_write_b32 %0, %4\n\t"
                 "v_accvgpr_write_b32 %1, %5\n\t"
                 "v_accvgpr_write_b32 %2, %6\n\t"
                 "v_accvgpr_write_b32 %3, %7"
                 : "=a"(r.x), "=a"(r.y), "=a"(r.z), "=a"(r.w)
                 : "v"(v.x), "v"(v.y), "v"(v.z), "v"(v.w));
    return r;
}
__device__ __forceinline__ i32x4 unpark_agpr(i32x4 a) {
    i32x4 r;
    asm("v_accvgpr_read_b32 %0, %4\n\t"
        "v_accvgpr_read_b32 %1, %5\n\t"
        "v_accvgpr_read_b32 %2, %6\n\t"
        "v_accvgpr_read_b32 %3, %7\n\t"
        "s_nop 1"
        : "=v"(r.x), "=v"(r.y), "=v"(r.z), "=v"(r.w)
        : "a"(a.x), "a"(a.y), "a"(a.z), "a"(a.w));
    return r;
}
__device__ __forceinline__ f32x4 mfma_v(i32x4 a, i32x4 b, f32x4 c) {
    return __builtin_amdgcn_mfma_f32_16x16x32_bf16(
        __builtin_bit_cast(bf16x8, a), __builtin_bit_cast(bf16x8, b), c, 0, 0, 0);
}

// ---------------------------------------------------------------------------
// K1: swizzled bf16 weights Wfull[288][1024] in MFMA B-frag order.
// Main region: [kit 0..8][ntile 0..63][lane] x 16B.
// Stream region (kits 4,7,8): [w][s][gate][u][lane] -- wave-major constant
// offsets (K2 uses s=0 (kit4), s=1 (kit7)).
// ---------------------------------------------------------------------------
__global__ __launch_bounds__(64) void build_wswz(
    const float* __restrict__ Wgx, const float* __restrict__ Wgh, const float* __restrict__ bg,
    const float* __restrict__ Wix, const float* __restrict__ Wih, const float* __restrict__ bi,
    const float* __restrict__ Wfx, const float* __restrict__ Wfh, const float* __restrict__ bf_,
    const float* __restrict__ Wox, const float* __restrict__ Woh, const float* __restrict__ bo,
    unsigned short* __restrict__ wswz, unsigned short* __restrict__ sbuf)
{
    int g   = blockIdx.x / NKIT;   // ntile
    int kit = blockIdx.x % NKIT;
    int lane = threadIdx.x;
    int n = g * 16 + (lane & 15);
    int q = n >> 8;
    int col = n & 255;
    const float* Wh = (q == 0) ? Wgh : (q == 1) ? Wih : (q == 2) ? Wfh : Woh;
    const float* Wx = (q == 0) ? Wgx : (q == 1) ? Wix : (q == 2) ? Wfx : Wox;
    const float* bb = (q == 0) ? bg  : (q == 1) ? bi  : (q == 2) ? bf_ : bo;
    int k0 = kit * 32 + (lane >> 4) * 8;

    int4 out;
    unsigned short* p = (unsigned short*)&out;
#pragma unroll
    for (int jx = 0; jx < 8; jx++) {
        int k = k0 + jx;
        float v = 0.0f;
        if (k < 256)             v = Wh[k * 256 + col];
        else if (k < 256 + EMBD) v = Wx[(k - 256) * 256 + col];
        else if (k == 266)       v = bb[col];
        p[jx] = f2bf(v);
    }
    ((int4*)wswz)[(kit * 64 + g) * 64 + lane] = out;

    if (kit == 4 || kit == 7 || kit == 8) {
        int s    = (kit == 4) ? 0 : (kit == 7) ? 1 : 2;
        int gate = g >> 4;
        int wv   = (g & 15) >> 1;
        int u    = g & 1;
        ((int4*)sbuf)[((((wv * 3 + s) * 4 + gate) * 2 + u) * 64) + lane] = out;
    }
}

// ---------------------------------------------------------------------------
// K2: persistent LSTM. 64 blocks x 512 threads (8 waves, 2 waves/SIMD;
// unified RF = 256/wave: 128 arch + 128 AGPR).
// Wave w owns hcols 32w+16u+l15 (u=0,1) x 4 gates: nt = gate*16 + 2w + u.
// B residency/wave: kits {0,1,2,3} parked AGPR (128 AGPR), kits {5,6} LDS
// (128 KB), kit {8} arch (32 regs), kits {4,7} streamed (128 KB/step/CU)
// via a SINGLE 4-frag rotating land buffer (16 regs): consume kit4 ->
// reissue kit7 (in-pass, ~20-MFMA cover) -> consume kit7 -> reissue
// next-pass kit4 (cross-pass cover). Arch demand ~100 << 128: R16->R17
// showed land 48->32 regs cut 1.6k cyc/step + 3 MB spill writebacks; this
// continues the dose (32->16). Success tell: VGPR_Count finally < 128.
// ---------------------------------------------------------------------------
__global__ __launch_bounds__(512)
__attribute__((amdgpu_waves_per_eu(2, 2)))
void lstm_main(
    const int*   __restrict__ xtok,   // [1024][1][256]
    const float* __restrict__ emb,    // [32000][10]
    const float* __restrict__ Wph,    // [256][10]
    const float* __restrict__ bp,     // [10]
    const unsigned short* __restrict__ wswz,
    const unsigned short* __restrict__ sbuf,
    float* __restrict__ out)          // [1024][10]
{
    __shared__ __align__(16) unsigned short A_lds[2][8 * 64 * 8];   // 16 KB (kits 0-7)
    __shared__ __align__(16) unsigned short A8_lds[2][64 * 8];      // 2 KB (kit 8)
    __shared__ __align__(16) i32x4 B_lds[2 * 64 * 64];              // 128 KB (kits 5,6)
    __shared__ float outacc[MB * 10];

    const int tid  = threadIdx.x;
    const int w    = tid >> 6;        // wave 0..7
    const int lane = tid & 63;
    const int quad = lane >> 4;
    const int l15  = lane & 15;
    const int blk  = blockIdx.x;

    const int m_x = tid >> 4;         // x-gather: batch row 0..15 (tid<256)
    const int e_x = tid & 15;         // emb element (valid if <10)

    const i32x4* Bg  = (const i32x4*)wswz;
    const i32x4* SBw = (const i32x4*)sbuf + (size_t)w * (3 * 4 * 2 * 64);

    // --- prologue: LDS B-cache (kits 5,6) ---
    for (int i = tid; i < 2 * 64 * 64; i += 512)
        B_lds[i] = Bg[5 * 4096 + i];

    // --- AGPR-parked B: kits 0..3, [kit][gate][u] = 32 frags = 128 AGPR ---
    i32x4 bag[4][4][2];
#pragma unroll
    for (int s = 0; s < 4; s++)
#pragma unroll
        for (int g = 0; g < 4; g++)
#pragma unroll
            for (int u = 0; u < 2; u++)
                bag[s][g][u] = park_agpr(
                    Bg[(s * 64 + g * 16 + 2 * w + u) * 64 + lane]);

    // --- arch-resident kit 8: [gate][u] = 8 frags = 32 regs ---
    i32x4 b8[4][2];
#pragma unroll
    for (int g = 0; g < 4; g++)
#pragma unroll
        for (int u = 0; u < 2; u++)
            b8[g][u] = Bg[(8 * 64 + g * 16 + 2 * w + u) * 64 + lane];

    // --- rotating land buffer: holds kit4(u=0) on loop entry ---
    i32x4 land[4];
#pragma unroll
    for (int g = 0; g < 4; g++)
        land[g] = SBw[(((0 * 4 + g) * 2 + 0) * 64) + lane];

    // --- init A double buffer: zeros, bias row (both), x_0 (buf 0) ---
    {
        int4 z4 = {0, 0, 0, 0};
        for (int i = tid; i < 1024; i += 512) ((int4*)A_lds)[i] = z4;
        if (tid < 128) ((int4*)A8_lds)[tid] = z4;
    }
    __syncthreads();
    if (tid < 16) {
        // kit8 local k=10 (bias=1.0): lp = m+16, elem 2
        A8_lds[0][(16 + tid) * 8 + 2] = 0x3F80;
        A8_lds[1][(16 + tid) * 8 + 2] = 0x3F80;
    }
    if (tid < 256 && e_x < EMBD) {
        int tok = xtok[(blk * MB + m_x) * T_STEPS + 0];
        float v = emb[tok * EMBD + e_x];
        A8_lds[0][(m_x + 16 * (e_x >> 3)) * 8 + (e_x & 7)] = f2bf(v);
    }
    __syncthreads();

    float c[2][4];
#pragma unroll
    for (int u = 0; u < 2; u++)
#pragma unroll
        for (int r = 0; r < 4; r++) c[u][r] = 0.0f;

    for (int t = 0; t < T_STEPS; t++) {
        const i32x4* Ab  = (const i32x4*)A_lds[t & 1];
        const i32x4* A8b = (const i32x4*)A8_lds[t & 1];
        unsigned short* Aw  = A_lds[(t + 1) & 1];
        unsigned short* A8w = A8_lds[(t + 1) & 1];

        // x(t+1) prefetch (independent; overlaps MFMA)
        float xval = 0.0f;
        const bool do_x = (t < T_STEPS - 1) && (tid < 256) && (e_x < EMBD);
        if ((t < T_STEPS - 1) && (tid < 256)) {
            int tok = xtok[(blk * MB + m_x) * T_STEPS + (t + 1)];
            if (e_x < EMBD) xval = emb[tok * EMBD + e_x];
        }

#pragma unroll
        for (int u = 0; u < 2; u++) {
            const int nu = 1 - u;  // next-pass index (t-invariant addresses)

            f32x4 acc[4];
#pragma unroll
            for (int g = 0; g < 4; g++) acc[g] = (f32x4){0.f, 0.f, 0.f, 0.f};

            // --- kit 4 (streamed; load landed last pass) ---
            {
                i32x4 a4 = Ab[4 * 64 + lane];
#pragma unroll
                for (int g = 0; g < 4; g++) acc[g] = mfma_v(a4, land[g], acc[g]);
            }
            // rotate: issue kit 7(u) into land (consumed ~20 MFMAs later)
#pragma unroll
            for (int g = 0; g < 4; g++)
                land[g] = SBw[(((1 * 4 + g) * 2 + u) * 64) + lane];

            // --- kit 8 (arch-resident) ---
            {
                i32x4 a8 = A8b[lane];
#pragma unroll
                for (int g = 0; g < 4; g++)
                    acc[g] = mfma_v(a8, b8[g][u], acc[g]);
            }
            // --- AGPR kits 0..3 (unpark per use) ---
#pragma unroll
            for (int s = 0; s < 4; s++) {
                i32x4 as_ = Ab[s * 64 + lane];
#pragma unroll
                for (int g = 0; g < 4; g++)
                    acc[g] = mfma_v(as_, unpark_agpr(bag[s][g][u]), acc[g]);
            }
            // --- LDS kit 5 ---
            {
                i32x4 a5 = Ab[5 * 64 + lane];
#pragma unroll
                for (int g = 0; g < 4; g++)
                    acc[g] = mfma_v(a5, B_lds[(g * 16 + 2 * w + u) * 64 + lane], acc[g]);
            }
            // --- kit 7 (streamed; issued this pass, ~20 MFMAs cover) ---
            {
                i32x4 a7 = Ab[7 * 64 + lane];
#pragma unroll
                for (int g = 0; g < 4; g++) acc[g] = mfma_v(a7, land[g], acc[g]);
            }
            // rotate: issue next pass's kit 4 (cross-pass/barrier cover)
#pragma unroll
            for (int g = 0; g < 4; g++)
                land[g] = SBw[(((0 * 4 + g) * 2 + nu) * 64) + lane];

            // --- LDS kit 6 ---
            {
                i32x4 a6 = Ab[6 * 64 + lane];
#pragma unroll
                for (int g = 0; g < 4; g++)
                    acc[g] = mfma_v(a6, B_lds[4096 + (g * 16 + 2 * w + u) * 64 + lane], acc[g]);
            }

            // gate math: z[m][n], m = quad*4+r, n = gate*256 + 32w + 16u + l15
            const int hcol = 32 * w + 16 * u + l15;
            const int lpbase = 16 * ((hcol >> 3) & 3);
#pragma unroll
            for (int r = 0; r < 4; r++) {
                float gg = tanh_fast(acc[0][r]);
                float ii = sig_fast(acc[1][r]);
                float ff = sig_fast(acc[2][r]);
                float oo = sig_fast(acc[3][r]);
                float cn = gg * ii + c[u][r] * ff;
                c[u][r] = cn;
                float hh = tanh_fast(cn) * oo;
                int m = quad * 4 + r;
                Aw[(w * 64 + m + lpbase) * 8 + (hcol & 7)] = f2bf(hh);
            }
        }
        if (t == T_STEPS - 1) break;
        if (do_x)
            A8w[(m_x + 16 * (e_x >> 3)) * 8 + (e_x & 7)] = f2bf(xval);
        __syncthreads();  // single barrier: A(t+1) complete
    }
    __syncthreads();

    // --- epilogue: re-read own h (bf16) from final A buffer, project ---
    const unsigned short* Af = A_lds[T_STEPS & 1];
    float part[4][10];
#pragma unroll
    for (int r = 0; r < 4; r++)
#pragma unroll
        for (int cl = 0; cl < 10; cl++) part[r][cl] = 0.0f;
#pragma unroll
    for (int u = 0; u < 2; u++) {
        const int hcol = 32 * w + 16 * u + l15;
        const int lpbase = 16 * ((hcol >> 3) & 3);
#pragma unroll
        for (int r = 0; r < 4; r++) {
            int m = quad * 4 + r;
            unsigned int hu = Af[(w * 64 + m + lpbase) * 8 + (hcol & 7)];
            union { unsigned int uu; float f; } cv; cv.uu = hu << 16;
            float hh = cv.f;
#pragma unroll
            for (int cl = 0; cl < 10; cl++)
                part[r][cl] += hh * Wph[hcol * 10 + cl];
        }
    }
#pragma unroll
    for (int off = 1; off < 16; off <<= 1)
#pragma unroll
        for (int r = 0; r < 4; r++)
#pragma unroll
            for (int cl = 0; cl < 10; cl++)
                part[r][cl] += __shfl_xor(part[r][cl], off, 64);

    if (tid < MB * 10) outacc[tid] = 0.0f;
    __syncthreads();
    if (l15 == 0) {
#pragma unroll
        for (int r = 0; r < 4; r++) {
            int m = quad * 4 + r;
#pragma unroll
            for (int cl = 0; cl < 10; cl++)
                atomicAdd(&outacc[m * 10 + cl], part[r][cl]);
        }
    }
    __syncthreads();
    if (tid < MB * 10) {
        int m = tid / 10, cl = tid - m * 10;
        out[(blk * MB + m) * 10 + cl] = outacc[tid] + bp[cl];
    }
}

extern "C" void kernel_launch(void* const* d_in, const int* in_sizes, int n_in,
                              void* d_out, int out_size, void* d_ws, size_t ws_size,
                              hipStream_t stream) {
    const int*   x    = (const int*)  d_in[0];
    const float* emb  = (const float*)d_in[1];
    const float* Wgx  = (const float*)d_in[2];
    const float* Wgh  = (const float*)d_in[3];
    const float* bg   = (const float*)d_in[4];
    const float* Wix  = (const float*)d_in[5];
    const float* Wih  = (const float*)d_in[6];
    const float* bi   = (const float*)d_in[7];
    const float* Wfx  = (const float*)d_in[8];
    const float* Wfh  = (const float*)d_in[9];
    const float* bf_  = (const float*)d_in[10];
    const float* Wox  = (const float*)d_in[11];
    const float* Woh  = (const float*)d_in[12];
    const float* bo   = (const float*)d_in[13];
    const float* Wph  = (const float*)d_in[14];
    const float* bp   = (const float*)d_in[15];

    char* ws = (char*)d_ws;
    unsigned short* wswz = (unsigned short*)ws;                   // 576 KB
    unsigned short* sbuf = (unsigned short*)(ws + 9 * 64 * 64 * 16); // 192 KB

    build_wswz<<<NBLK * NKIT, 64, 0, stream>>>(Wgx, Wgh, bg, Wix, Wih, bi,
                                               Wfx, Wfh, bf_, Wox, Woh, bo,
                                               wswz, sbuf);
    lstm_main<<<NBLK, 512, 0, stream>>>(x, emb, Wph, bp, wswz, sbuf,
                                        (float*)d_out);
}